// Round 1
// baseline (147.126 us; speedup 1.0000x reference)
//
#include <hip/hip_runtime.h>

// MMD over persistence diagrams, RBF kernel, WIDTH=1, DECAY=1.
// out = sum_b weights[b]/ns[b]^2 * (S_XX - 2 S_XY + S_YY)
// S_AB = sum_{n,m} exp(-max(||a_n-b_m||^2,0)/WIDTH) * wa_n * wb_m
// with points mapped (birth,death)->(birth,lifetime), w = lifetime^DECAY.

#define LOG2E_F 1.44269504088896340736f
constexpr float WIDTH = 1.0f;

struct __align__(16) P4 { float x, y, n, w; };  // coord x, coord y(=lifetime), x^2+y^2, weight

// ---------------- prep: (birth,death) -> (x, l, nrm, w) float4; zero the accumulator ----
__global__ void prep_kernel(const float* __restrict__ X, const float* __restrict__ Y,
                            P4* __restrict__ PX, P4* __restrict__ PY,
                            int nx_total, int ny_total, double* __restrict__ acc) {
    int i = blockIdx.x * blockDim.x + threadIdx.x;
    if (i == 0) *acc = 0.0;
    if (i < nx_total) {
        float b = X[2 * i], d = X[2 * i + 1];
        float l = d - b;                 // lifetime >= 0
        P4 p; p.x = b; p.y = l; p.n = b * b + l * l; p.w = l;  // DECAY==1 -> w = l
        PX[i] = p;
    }
    if (i < ny_total) {
        float b = Y[2 * i], d = Y[2 * i + 1];
        float l = d - b;
        P4 p; p.x = b; p.y = l; p.n = b * b + l * l; p.w = l;
        PY[i] = p;
    }
}

// ---------------- main: one thread per row n, loop over all m (wave-uniform B loads) ----
__global__ __launch_bounds__(256) void mmd_kernel(
    const P4* __restrict__ PXall, const P4* __restrict__ PYall,
    const float* __restrict__ weights, const float* __restrict__ ns,
    int N, int M, double* __restrict__ acc) {

    const int b    = blockIdx.z;
    const int term = blockIdx.y;  // 0: XX, 1: XY, 2: YY

    const P4* __restrict__ A  = (term == 2) ? (PYall + (size_t)b * M) : (PXall + (size_t)b * N);
    const P4* __restrict__ Bp = (term == 0) ? (PXall + (size_t)b * N) : (PYall + (size_t)b * M);
    const int nrows = (term == 2) ? M : N;
    const int mlen  = (term == 0) ? N : M;
    const float sign = (term == 1) ? -2.0f : 1.0f;

    const int n = blockIdx.x * blockDim.x + threadIdx.x;

    float thread_val = 0.0f;
    if (n < nrows) {
        P4 a = A[n];
        const float c  = LOG2E_F / WIDTH;
        const float nc = -c;
        // exp(-d2/W) = exp2(c*(2 ax bx + 2 ay by - na - nb)), clamped to <= 2^0
        const float Ax = 2.0f * c * a.x;
        const float Ay = 2.0f * c * a.y;
        const float An = nc * a.n;

        float s0 = 0.0f, s1 = 0.0f, s2 = 0.0f, s3 = 0.0f;
        int m = 0;
        for (; m + 4 <= mlen; m += 4) {
            P4 p0 = Bp[m + 0];
            P4 p1 = Bp[m + 1];
            P4 p2 = Bp[m + 2];
            P4 p3 = Bp[m + 3];
            float t0 = fmaf(Ax, p0.x, fmaf(Ay, p0.y, fmaf(nc, p0.n, An)));
            float t1 = fmaf(Ax, p1.x, fmaf(Ay, p1.y, fmaf(nc, p1.n, An)));
            float t2 = fmaf(Ax, p2.x, fmaf(Ay, p2.y, fmaf(nc, p2.n, An)));
            float t3 = fmaf(Ax, p3.x, fmaf(Ay, p3.y, fmaf(nc, p3.n, An)));
            t0 = fminf(t0, 0.0f);
            t1 = fminf(t1, 0.0f);
            t2 = fminf(t2, 0.0f);
            t3 = fminf(t3, 0.0f);
            float e0 = __builtin_amdgcn_exp2f(t0);
            float e1 = __builtin_amdgcn_exp2f(t1);
            float e2 = __builtin_amdgcn_exp2f(t2);
            float e3 = __builtin_amdgcn_exp2f(t3);
            s0 = fmaf(e0, p0.w, s0);
            s1 = fmaf(e1, p1.w, s1);
            s2 = fmaf(e2, p2.w, s2);
            s3 = fmaf(e3, p3.w, s3);
        }
        for (; m < mlen; ++m) {
            P4 p0 = Bp[m];
            float t0 = fmaf(Ax, p0.x, fmaf(Ay, p0.y, fmaf(nc, p0.n, An)));
            t0 = fminf(t0, 0.0f);
            s0 = fmaf(__builtin_amdgcn_exp2f(t0), p0.w, s0);
        }
        thread_val = a.w * ((s0 + s1) + (s2 + s3));
    }

    // ---- block reduction in double (256 threads = 4 waves) ----
    double v = (double)thread_val;
    #pragma unroll
    for (int off = 32; off > 0; off >>= 1)
        v += __shfl_down(v, off, 64);

    __shared__ double lds[4];
    const int wave = threadIdx.x >> 6;
    const int lane = threadIdx.x & 63;
    if (lane == 0) lds[wave] = v;
    __syncthreads();
    if (threadIdx.x == 0) {
        double tot = (lds[0] + lds[1]) + (lds[2] + lds[3]);
        double nsb = (double)ns[b];
        double scale = (double)sign * (double)weights[b] / (nsb * nsb);
        atomicAdd(acc, tot * scale);
    }
}

__global__ void finalize_kernel(const double* __restrict__ acc, float* __restrict__ out) {
    if (threadIdx.x == 0 && blockIdx.x == 0) out[0] = (float)(*acc);
}

extern "C" void kernel_launch(void* const* d_in, const int* in_sizes, int n_in,
                              void* d_out, int out_size, void* d_ws, size_t ws_size,
                              hipStream_t stream) {
    const float* X  = (const float*)d_in[0];
    const float* Y  = (const float*)d_in[1];
    const float* W  = (const float*)d_in[2];
    const float* NS = (const float*)d_in[3];

    const int B = in_sizes[2];
    const int N = in_sizes[0] / (2 * B);
    const int M = in_sizes[1] / (2 * B);

    // workspace layout: [double acc][pad to 16][PX: B*N P4][PY: B*M P4]
    double* acc = (double*)d_ws;
    P4* PX = (P4*)((char*)d_ws + 16);
    P4* PY = PX + (size_t)B * N;

    const int nx_total = B * N;
    const int ny_total = B * M;
    const int prep_total = nx_total > ny_total ? nx_total : ny_total;

    prep_kernel<<<(prep_total + 255) / 256, 256, 0, stream>>>(X, Y, PX, PY, nx_total, ny_total, acc);

    const int rows_max = N > M ? N : M;
    dim3 grid((rows_max + 255) / 256, 3, B);
    mmd_kernel<<<grid, 256, 0, stream>>>(PX, PY, W, NS, N, M, acc);

    finalize_kernel<<<1, 64, 0, stream>>>(acc, (float*)d_out);
}